// Round 7
// baseline (222.145 us; speedup 1.0000x reference)
//
#include <hip/hip_runtime.h>

// Problem constants (static from reference setup_inputs)
constexpr int BB = 8, CC = 4, HH = 1024, WW = 1024, CROP = 5;
constexpr int HC = HH - 2 * CROP, WC = WW - 2 * CROP;   // 1014 x 1014
constexpr int HW = HH * WW;
constexpr float AA = -0.75f;                            // PyTorch bicubic A

constexpr int CHUNK = 224;                   // pixels per segment
constexpr int NCHK = 5;                      // chunks per image row (5*224 >= 1014)
constexpr int NSEG = BB * HC * NCHK;         // 40560 segments
constexpr int PBLK = 1536;                   // 6 blocks/CU persistent
constexpr int SROW = 12;                     // staged rows: y-5 .. y+6
constexpr int SSTR = 260;                    // LDS row stride (floats); 260%32=4 -> no conflicts
constexpr int SFL = SROW * SSTR;             // 3120 floats = 12.48 KB per buffer

typedef __attribute__((address_space(1))) const void gv_t;
typedef __attribute__((address_space(3))) void lv_t;

// reflection valid for |i| <= 2046
__device__ __forceinline__ int reflect_small(int i) {
    int r = i < 0 ? -i : i;
    return r > (HH - 1) ? 2 * (HH - 1) - r : r;
}

__device__ __forceinline__ void cubic_w(float t, float& w0, float& w1,
                                        float& w2, float& w3) {
    float t1 = t + 1.0f;
    w0 = ((AA * t1 - 5.0f * AA) * t1 + 8.0f * AA) * t1 - 4.0f * AA;
    w1 = ((AA + 2.0f) * t - (AA + 3.0f)) * t * t + 1.0f;
    float s = 1.0f - t;
    w2 = ((AA + 2.0f) * s - (AA + 3.0f)) * s * s + 1.0f;
    float s2 = 2.0f - t;
    w3 = ((AA * s2 - 5.0f * AA) * s2 + 8.0f * AA) * s2 - 4.0f * AA;
}

// rare fallback: scalar reflected global taps for one pixel, all 4 channels
__device__ __noinline__ float px_slow(const float* __restrict__ tgt_b,
                                      const float* __restrict__ in_b, int pix,
                                      int bx, int by, float wx0, float wx1,
                                      float wx2, float wx3, float wy0,
                                      float wy1, float wy2, float wy3) {
    const int r0 = reflect_small(by - 1) * WW;
    const int r1 = reflect_small(by) * WW;
    const int r2 = reflect_small(by + 1) * WW;
    const int r3 = reflect_small(by + 2) * WW;
    const int c0 = reflect_small(bx - 1);
    const int c1 = reflect_small(bx);
    const int c2 = reflect_small(bx + 1);
    const int c3 = reflect_small(bx + 2);
    float acc = 0.0f;
#pragma unroll
    for (int c = 0; c < CC; ++c) {
        const float* tb = tgt_b + c * HW;
        float q0 = wx0 * tb[r0 + c0] + wx1 * tb[r0 + c1] + wx2 * tb[r0 + c2] +
                   wx3 * tb[r0 + c3];
        float q1 = wx0 * tb[r1 + c0] + wx1 * tb[r1 + c1] + wx2 * tb[r1 + c2] +
                   wx3 * tb[r1 + c3];
        float q2 = wx0 * tb[r2 + c0] + wx1 * tb[r2 + c1] + wx2 * tb[r2 + c2] +
                   wx3 * tb[r2 + c3];
        float q3 = wx0 * tb[r3 + c0] + wx1 * tb[r3 + c1] + wx2 * tb[r3 + c2] +
                   wx3 * tb[r3 + c3];
        float v = wy0 * q0 + wy1 * q1 + wy2 * q2 + wy3 * q3;
        acc += fabsf(in_b[c * HW + pix] - v);
    }
    return acc;
}

__global__ __launch_bounds__(256, 6) void warp_loss_k(
    const float* __restrict__ input, const float* __restrict__ target,
    const float* __restrict__ flow, float* __restrict__ wsbuf) {
    __shared__ float cache[2][SFL];
    const int tid = (int)threadIdx.x;
    const int wv = tid >> 6, lane = tid & 63;
    float lsum = 0.0f;

    for (int seg = blockIdx.x; seg < NSEG; seg += PBLK) {
        const int chunk = seg % NCHK;
        const int row = seg / NCHK;
        const int y = row % HC + CROP;
        const int b = row / HC;
        const int x0 = CROP + chunk * CHUNK;
        const int x = x0 + tid;
        const bool valid = (tid < CHUNK) && (x <= 1018);

        int wscol = (x0 - 16) & ~3;
        wscol = wscol < 0 ? 0 : (wscol > WW - 256 ? WW - 256 : wscol);

        const float* tgt_b = target + (size_t)b * CC * HW;
        const float* in_b = input + (size_t)b * CC * HW;
        const float* flow_b = flow + (size_t)b * 2 * HW;

        const int xc = x <= 1018 ? x : 1018;   // clamp: harmless loads for tail lanes
        const int pix = y * WW + xc;
        const float dx = flow_b[pix];
        const float dy = flow_b[HW + pix];
        const float i0v = in_b[pix];
        const float i1v = in_b[HW + pix];
        const float i2v = in_b[2 * HW + pix];
        const float i3v = in_b[3 * HW + pix];

        const float fx = (float)xc + dx;
        const float fy = (float)y + dy;
        const float bxf = floorf(fx), byf = floorf(fy);
        const int bx = (int)bxf, by = (int)byf;
        const float tx = fx - bxf, ty = fy - byf;

        float wx0, wx1, wx2, wx3, wy0, wy1, wy2, wy3;
        cubic_w(tx, wx0, wx1, wx2, wx3);
        cubic_w(ty, wy0, wy1, wy2, wy3);

        // fast path: all 16 taps inside staged window, no reflection involved
        const bool rows_ok = ((unsigned)(by - (y - 4)) <= 8u) && (by <= 1021);
        const bool cols_ok = (bx - 1 >= wscol) && (bx + 2 <= wscol + 255);
        const bool fast = valid && rows_ok && cols_ok;
        const bool slow = valid && !fast;

        const int l0 = (by - y + 4) * SSTR + (bx - 1 - wscol);

        // per-wave staging geometry: wave wv stages rows {wv, wv+4, wv+8}
        const int ysrc0 = reflect_small(y - 5 + wv);
        const int ysrc1 = reflect_small(y - 5 + wv + 4);
        const int ysrc2 = reflect_small(y - 5 + wv + 8);
        const int gcol = wscol + lane * 4;

        __builtin_amdgcn_sched_barrier(0);  // pin flow/input loads before staging
        // stage ch0 -> buf0 (safe: prev segment's trailing barrier passed)
        {
            const float* pl = tgt_b;
            __builtin_amdgcn_global_load_lds(
                (gv_t*)(pl + (size_t)ysrc0 * WW + gcol),
                (lv_t*)&cache[0][(wv + 0) * SSTR], 16, 0, 0);
            __builtin_amdgcn_global_load_lds(
                (gv_t*)(pl + (size_t)ysrc1 * WW + gcol),
                (lv_t*)&cache[0][(wv + 4) * SSTR], 16, 0, 0);
            __builtin_amdgcn_global_load_lds(
                (gv_t*)(pl + (size_t)ysrc2 * WW + gcol),
                (lv_t*)&cache[0][(wv + 8) * SSTR], 16, 0, 0);
        }

#pragma unroll
        for (int ch = 0; ch < CC; ++ch) {
            if (ch < 3) {
                // prefetch next channel into the other buffer
                const float* pl = tgt_b + (ch + 1) * HW;
                const int bufn = (ch + 1) & 1;
                __builtin_amdgcn_global_load_lds(
                    (gv_t*)(pl + (size_t)ysrc0 * WW + gcol),
                    (lv_t*)&cache[bufn][(wv + 0) * SSTR], 16, 0, 0);
                __builtin_amdgcn_global_load_lds(
                    (gv_t*)(pl + (size_t)ysrc1 * WW + gcol),
                    (lv_t*)&cache[bufn][(wv + 4) * SSTR], 16, 0, 0);
                __builtin_amdgcn_global_load_lds(
                    (gv_t*)(pl + (size_t)ysrc2 * WW + gcol),
                    (lv_t*)&cache[bufn][(wv + 8) * SSTR], 16, 0, 0);
                asm volatile("s_waitcnt vmcnt(3)" ::: "memory");  // my cur-buf rows landed
            } else {
                asm volatile("s_waitcnt vmcnt(0)" ::: "memory");  // last channel: drain
            }
            __builtin_amdgcn_sched_barrier(0);
            __builtin_amdgcn_s_barrier();      // raw: no vmcnt(0) drain of prefetch
            __builtin_amdgcn_sched_barrier(0);

            if (fast) {
                const float* base = &cache[ch & 1][l0];
                float v;
                {
                    float q = base[0] * wx0 + base[1] * wx1 + base[2] * wx2 +
                              base[3] * wx3;
                    v = wy0 * q;
                }
                {
                    const float* r = base + SSTR;
                    float q = r[0] * wx0 + r[1] * wx1 + r[2] * wx2 + r[3] * wx3;
                    v += wy1 * q;
                }
                {
                    const float* r = base + 2 * SSTR;
                    float q = r[0] * wx0 + r[1] * wx1 + r[2] * wx2 + r[3] * wx3;
                    v += wy2 * q;
                }
                {
                    const float* r = base + 3 * SSTR;
                    float q = r[0] * wx0 + r[1] * wx1 + r[2] * wx2 + r[3] * wx3;
                    v += wy3 * q;
                }
                const float iv = (ch == 0) ? i0v : (ch == 1) ? i1v
                                 : (ch == 2) ? i2v : i3v;
                lsum += fabsf(iv - v);
            }
            __builtin_amdgcn_sched_barrier(0);
            __builtin_amdgcn_s_barrier();  // all reads of this buffer done before re-stage
        }

        if (slow) {
            lsum += px_slow(tgt_b, in_b, pix, bx, by, wx0, wx1, wx2, wx3, wy0,
                            wy1, wy2, wy3);
        }
    }

    // wave-64 shuffle reduction + per-block partial (no global atomic)
#pragma unroll
    for (int off = 32; off > 0; off >>= 1) lsum += __shfl_down(lsum, off);

    __shared__ float sm[4];
    if (lane == 0) sm[wv] = lsum;
    __syncthreads();
    if (tid == 0) wsbuf[blockIdx.x] = sm[0] + sm[1] + sm[2] + sm[3];
}

__global__ __launch_bounds__(1024) void reduce_k(const float* __restrict__ ws,
                                                 float* __restrict__ out) {
    float s = 0.0f;
    for (int i = threadIdx.x; i < PBLK; i += 1024) s += ws[i];
#pragma unroll
    for (int off = 32; off > 0; off >>= 1) s += __shfl_down(s, off);
    __shared__ float sm[16];
    const int lane = threadIdx.x & 63;
    const int wv = threadIdx.x >> 6;
    if (lane == 0) sm[wv] = s;
    __syncthreads();
    if (threadIdx.x == 0) {
        float t = 0.0f;
#pragma unroll
        for (int i = 0; i < 16; ++i) t += sm[i];
        constexpr float inv_count = 1.0f / ((float)BB * CC * HC * WC);
        out[0] = t * inv_count;
    }
}

extern "C" void kernel_launch(void* const* d_in, const int* in_sizes, int n_in,
                              void* d_out, int out_size, void* d_ws,
                              size_t ws_size, hipStream_t stream) {
    const float* input = (const float*)d_in[0];
    const float* target = (const float*)d_in[1];
    const float* flow = (const float*)d_in[2];
    float* ws = (float*)d_ws;
    float* out = (float*)d_out;

    warp_loss_k<<<PBLK, 256, 0, stream>>>(input, target, flow, ws);
    reduce_k<<<1, 1024, 0, stream>>>(ws, out);
}